// Round 1
// baseline (1060.723 us; speedup 1.0000x reference)
//
#include <hip/hip_runtime.h>

#define N_NODES 100000
#define IN_CH 128
#define HIDDEN 128
#define OUT_CH 64
#define N_POS 600000
#define N_NEG 600000

// ---------------- degree / dinv ----------------
__global__ void deg_count(const int* __restrict__ dst, float* __restrict__ deg, int n_edges) {
    int i = blockIdx.x * blockDim.x + threadIdx.x;
    if (i < n_edges) atomicAdd(&deg[dst[i]], 1.0f);
}

__global__ void dinv_finalize(float* __restrict__ deg, int n) {
    int i = blockIdx.x * blockDim.x + threadIdx.x;
    if (i < n) deg[i] = rsqrtf(deg[i] + 1.0f);
}

// ---------------- linear: H[n, 0:M] = X[n, 0:K] @ W[K, M] ----------------
template <int K, int M>
__global__ void linear_kernel(const float* __restrict__ X, const float* __restrict__ W,
                              float* __restrict__ H, int n) {
    constexpr int NPB = 256 / M;  // nodes per block
    __shared__ float xs[NPB][K];
    int node0 = blockIdx.x * NPB;
    for (int idx = threadIdx.x; idx < NPB * K; idx += 256) {
        int ln = idx / K, k = idx % K;
        int nn = node0 + ln;
        xs[ln][k] = (nn < n) ? X[(size_t)nn * K + k] : 0.0f;
    }
    __syncthreads();
    int ln = threadIdx.x / M;
    int j  = threadIdx.x % M;
    int node = node0 + ln;
    if (node >= n) return;
    float acc = 0.0f;
#pragma unroll 16
    for (int k = 0; k < K; ++k) acc += xs[ln][k] * W[k * M + j];
    H[(size_t)node * M + j] = acc;
}

// ---------------- scatter: AGG[dst] += H[src] * dinv[src]*dinv[dst] ----------------
template <int F>
__global__ void scatter_edges(const int* __restrict__ src, const int* __restrict__ dst,
                              const float* __restrict__ dinv, const float* __restrict__ H,
                              float* __restrict__ AGG, int n_edges) {
    long long idx = (long long)blockIdx.x * blockDim.x + threadIdx.x;
    long long total = (long long)n_edges * F;
    if (idx >= total) return;
    int e = (int)(idx / F);
    int f = (int)(idx % F);
    int s = src[e], d = dst[e];
    float norm = dinv[s] * dinv[d];
    atomicAdd(&AGG[(size_t)d * F + f], H[(size_t)s * F + f] * norm);
}

// ---------------- finalize: AGG = (AGG + H*dinv^2 + b), optional relu ----------------
template <int F, bool RELU>
__global__ void finalize_kernel(const float* __restrict__ H, const float* __restrict__ dinv,
                                const float* __restrict__ b, float* __restrict__ AGG, int n) {
    long long idx = (long long)blockIdx.x * blockDim.x + threadIdx.x;
    if (idx >= (long long)n * F) return;
    int node = (int)(idx / F);
    int f    = (int)(idx % F);
    float di = dinv[node];
    float v = AGG[idx] + H[idx] * di * di + b[f];
    AGG[idx] = RELU ? fmaxf(v, 0.0f) : v;
}

// ---------------- decode: out[e] = dot64(Z[a], Z[b]) ----------------
__global__ void decode_kernel(const int* __restrict__ pos, const int* __restrict__ neg,
                              const float* __restrict__ Z, float* __restrict__ out) {
    int wave = threadIdx.x >> 6;
    int lane = threadIdx.x & 63;
    int e = blockIdx.x * 4 + wave;
    if (e >= N_POS + N_NEG) return;
    int a, bb;
    if (e < N_POS) {
        a  = pos[e];
        bb = pos[N_POS + e];
    } else {
        int e2 = e - N_POS;
        a  = neg[e2];
        bb = neg[N_NEG + e2];
    }
    float v = Z[(size_t)a * OUT_CH + lane] * Z[(size_t)bb * OUT_CH + lane];
#pragma unroll
    for (int off = 32; off > 0; off >>= 1) v += __shfl_down(v, off, 64);
    if (lane == 0) out[e] = v;
}

extern "C" void kernel_launch(void* const* d_in, const int* in_sizes, int n_in,
                              void* d_out, int out_size, void* d_ws, size_t ws_size,
                              hipStream_t stream) {
    const float* x   = (const float*)d_in[0];
    const int*   pos = (const int*)d_in[1];  // [2 * N_POS] row-major: row0 = src, row1 = dst
    const int*   neg = (const int*)d_in[2];
    const float* W1  = (const float*)d_in[3];
    const float* b1  = (const float*)d_in[4];
    const float* W2  = (const float*)d_in[5];
    const float* b2  = (const float*)d_in[6];
    float* out = (float*)d_out;

    float* A    = (float*)d_ws;                       // N*128 (h1; later h2 + z2)
    float* B    = A + (size_t)N_NODES * 128;          // N*128 (agg1 / z1)
    float* dinv = B + (size_t)N_NODES * 128;          // N
    float* h2   = A;                                  // N*64
    float* z2   = A + (size_t)N_NODES * 64;           // N*64

    const int* pos_src = pos;
    const int* pos_dst = pos + N_POS;

    // 1. degrees -> dinv
    hipMemsetAsync(dinv, 0, N_NODES * sizeof(float), stream);
    deg_count<<<(N_POS + 255) / 256, 256, 0, stream>>>(pos_dst, dinv, N_POS);
    dinv_finalize<<<(N_NODES + 255) / 256, 256, 0, stream>>>(dinv, N_NODES);

    // 2. h1 = x @ W1
    linear_kernel<IN_CH, HIDDEN><<<(N_NODES + 1) / 2, 256, 0, stream>>>(x, W1, A, N_NODES);

    // 3. agg1 = scatter(h1), z1 = relu(agg1 + h1*dinv^2 + b1)
    hipMemsetAsync(B, 0, (size_t)N_NODES * HIDDEN * sizeof(float), stream);
    {
        long long tot = (long long)N_POS * HIDDEN;
        scatter_edges<HIDDEN><<<(int)((tot + 255) / 256), 256, 0, stream>>>(
            pos_src, pos_dst, dinv, A, B, N_POS);
        long long tn = (long long)N_NODES * HIDDEN;
        finalize_kernel<HIDDEN, true><<<(int)((tn + 255) / 256), 256, 0, stream>>>(
            A, dinv, b1, B, N_NODES);
    }

    // 4. h2 = z1 @ W2
    linear_kernel<HIDDEN, OUT_CH><<<(N_NODES + 3) / 4, 256, 0, stream>>>(B, W2, h2, N_NODES);

    // 5. agg2 = scatter(h2), z2 = agg2 + h2*dinv^2 + b2
    hipMemsetAsync(z2, 0, (size_t)N_NODES * OUT_CH * sizeof(float), stream);
    {
        long long tot = (long long)N_POS * OUT_CH;
        scatter_edges<OUT_CH><<<(int)((tot + 255) / 256), 256, 0, stream>>>(
            pos_src, pos_dst, dinv, h2, z2, N_POS);
        long long tn = (long long)N_NODES * OUT_CH;
        finalize_kernel<OUT_CH, false><<<(int)((tn + 255) / 256), 256, 0, stream>>>(
            h2, dinv, b2, z2, N_NODES);
    }

    // 6. decode
    decode_kernel<<<(N_POS + N_NEG + 3) / 4, 256, 0, stream>>>(pos, neg, z2, out);
}

// Round 2
// 599.370 us; speedup vs baseline: 1.7697x; 1.7697x over previous
//
#include <hip/hip_runtime.h>

#define N_NODES 100000
#define IN_CH 128
#define HIDDEN 128
#define OUT_CH 64
#define N_POS 600000
#define N_NEG 600000

// ================= CSR build =================
__global__ void hist_count(const int* __restrict__ dst, int* __restrict__ hist, int n_edges) {
    int i = blockIdx.x * blockDim.x + threadIdx.x;
    if (i < n_edges) atomicAdd(&hist[dst[i]], 1);
}

// per-1024-chunk sums
__global__ void scan_reduce(const int* __restrict__ hist, int* __restrict__ partials, int n) {
    __shared__ int sdata[256];
    int b = blockIdx.x, t = threadIdx.x;
    int base = b * 1024;
    int s = 0;
    for (int i = t; i < 1024; i += 256) {
        int idx = base + i;
        s += (idx < n) ? hist[idx] : 0;
    }
    sdata[t] = s;
    __syncthreads();
    for (int off = 128; off > 0; off >>= 1) {
        if (t < off) sdata[t] += sdata[t + off];
        __syncthreads();
    }
    if (t == 0) partials[b] = sdata[0];
}

// exclusive scan of partials (nb <= 128), single block of 128 threads
__global__ void scan_partials(int* __restrict__ partials, int nb) {
    __shared__ int tmp[128];
    int t = threadIdx.x;
    int v = (t < nb) ? partials[t] : 0;
    tmp[t] = v;
    __syncthreads();
    for (int off = 1; off < 128; off <<= 1) {
        int a = (t >= off) ? tmp[t - off] : 0;
        __syncthreads();
        tmp[t] += a;
        __syncthreads();
    }
    if (t < nb) partials[t] = tmp[t] - v;  // exclusive
}

// rowstart/cursor/dinv from hist + scanned partials
__global__ void scan_final(const int* __restrict__ hist, const int* __restrict__ partials,
                           int* __restrict__ rowstart, int* __restrict__ cursor,
                           float* __restrict__ dinv, int n) {
    __shared__ int tsum[256];
    int t = threadIdx.x, b = blockIdx.x;
    int base = b * 1024 + t * 4;
    int v[4];
    int s = 0;
#pragma unroll
    for (int j = 0; j < 4; j++) {
        int i = base + j;
        v[j] = (i < n) ? hist[i] : 0;
        s += v[j];
    }
    tsum[t] = s;
    __syncthreads();
    for (int off = 1; off < 256; off <<= 1) {
        int a = (t >= off) ? tsum[t - off] : 0;
        __syncthreads();
        tsum[t] += a;
        __syncthreads();
    }
    int offset = partials[b] + (tsum[t] - s);
#pragma unroll
    for (int j = 0; j < 4; j++) {
        int i = base + j;
        if (i < n) {
            rowstart[i] = offset;
            cursor[i] = offset;
            dinv[i] = rsqrtf((float)v[j] + 1.0f);
            offset += v[j];
        }
    }
    if (b == 0 && t == 0) rowstart[n] = N_POS;
}

__global__ void csr_fill(const int* __restrict__ src, const int* __restrict__ dst,
                         int* __restrict__ cursor, int* __restrict__ adj, int n_edges) {
    int e = blockIdx.x * blockDim.x + threadIdx.x;
    if (e < n_edges) {
        int p = atomicAdd(&cursor[dst[e]], 1);
        adj[p] = src[e];
    }
}

// ================= tiled fp32 GEMM: H[n,M] = X[n,128] @ W[128,M] =================
// TILE 64 nodes; thread computes 4 nodes x 4 cols; W + padded X tile in LDS.
template <int M, int THREADS>
__global__ __launch_bounds__(THREADS) void linear2(const float* __restrict__ X,
                                                   const float* __restrict__ W,
                                                   float* __restrict__ H, int n) {
    constexpr int K = 128;
    constexpr int TN = 64;
    constexpr int XS = 132;  // padded row stride (floats), 16B-aligned rows
    __shared__ float Ws[K * M];
    __shared__ float Xs[TN * XS];
    int tid = threadIdx.x;
    int node0 = blockIdx.x * TN;

    for (int q = tid; q < K * M / 4; q += THREADS)
        ((float4*)Ws)[q] = ((const float4*)W)[q];
    for (int q = tid; q < TN * K / 4; q += THREADS) {
        int node = q >> 5;   // 32 float4 per row
        int k4 = q & 31;
        int gn = node0 + node;
        float4 v = (gn < n) ? ((const float4*)(X + (size_t)gn * K))[k4] : float4{0, 0, 0, 0};
        ((float4*)(Xs + node * XS))[k4] = v;
    }
    __syncthreads();

    int tn = tid & 15;        // node group: nodes tn + 16*i
    int tj = tid >> 4;        // col group: cols tj*4 .. tj*4+3
    float acc[4][4] = {};
    for (int k = 0; k < K; k += 4) {
        float4 xa[4], wb[4];
#pragma unroll
        for (int i = 0; i < 4; i++)
            xa[i] = *(const float4*)(Xs + (tn + 16 * i) * XS + k);
#pragma unroll
        for (int q = 0; q < 4; q++)
            wb[q] = *(const float4*)(Ws + (k + q) * M + tj * 4);
#pragma unroll
        for (int i = 0; i < 4; i++) {
            float xk[4] = {xa[i].x, xa[i].y, xa[i].z, xa[i].w};
#pragma unroll
            for (int q = 0; q < 4; q++) {
                acc[i][0] += xk[q] * wb[q].x;
                acc[i][1] += xk[q] * wb[q].y;
                acc[i][2] += xk[q] * wb[q].z;
                acc[i][3] += xk[q] * wb[q].w;
            }
        }
    }
#pragma unroll
    for (int i = 0; i < 4; i++) {
        int gn = node0 + tn + 16 * i;
        if (gn < n)
            *(float4*)(H + (size_t)gn * M + tj * 4) =
                float4{acc[i][0], acc[i][1], acc[i][2], acc[i][3]};
    }
}

// ================= fused pull aggregation + self-loop + bias (+relu) =================
// one 64-lane wave per dst node
template <int F, bool RELU>
__global__ void agg_pull(const int* __restrict__ rowstart, const int* __restrict__ adj,
                         const float* __restrict__ dinv, const float* __restrict__ H,
                         const float* __restrict__ bias, float* __restrict__ Z, int n) {
    int wave = threadIdx.x >> 6;
    int lane = threadIdx.x & 63;
    int node = blockIdx.x * (blockDim.x >> 6) + wave;
    if (node >= n) return;
    float dn = dinv[node];
    int rs = rowstart[node], re = rowstart[node + 1];
    if (F == 128) {
        float2 acc = {0.0f, 0.0f};
        for (int p = rs; p < re; ++p) {
            int s = adj[p];
            float w = dinv[s] * dn;
            float2 hv = *(const float2*)(H + (size_t)s * F + lane * 2);
            acc.x += hv.x * w;
            acc.y += hv.y * w;
        }
        float2 hv = *(const float2*)(H + (size_t)node * F + lane * 2);
        float2 bv = *(const float2*)(bias + lane * 2);
        float vx = acc.x + hv.x * dn * dn + bv.x;
        float vy = acc.y + hv.y * dn * dn + bv.y;
        if (RELU) {
            vx = fmaxf(vx, 0.0f);
            vy = fmaxf(vy, 0.0f);
        }
        *(float2*)(Z + (size_t)node * F + lane * 2) = float2{vx, vy};
    } else {  // F == 64
        float acc = 0.0f;
        for (int p = rs; p < re; ++p) {
            int s = adj[p];
            acc += H[(size_t)s * F + lane] * (dinv[s] * dn);
        }
        float v = acc + H[(size_t)node * F + lane] * dn * dn + bias[lane];
        if (RELU) v = fmaxf(v, 0.0f);
        Z[(size_t)node * F + lane] = v;
    }
}

// ================= decode: out[e] = dot64(Z[a], Z[b]) =================
__global__ void decode_kernel(const int* __restrict__ pos, const int* __restrict__ neg,
                              const float* __restrict__ Z, float* __restrict__ out) {
    int wave = threadIdx.x >> 6;
    int lane = threadIdx.x & 63;
    int e = blockIdx.x * 4 + wave;
    if (e >= N_POS + N_NEG) return;
    int a, bb;
    if (e < N_POS) {
        a = pos[e];
        bb = pos[N_POS + e];
    } else {
        int e2 = e - N_POS;
        a = neg[e2];
        bb = neg[N_NEG + e2];
    }
    float v = Z[(size_t)a * OUT_CH + lane] * Z[(size_t)bb * OUT_CH + lane];
#pragma unroll
    for (int off = 32; off > 0; off >>= 1) v += __shfl_down(v, off, 64);
    if (lane == 0) out[e] = v;
}

extern "C" void kernel_launch(void* const* d_in, const int* in_sizes, int n_in,
                              void* d_out, int out_size, void* d_ws, size_t ws_size,
                              hipStream_t stream) {
    const float* x = (const float*)d_in[0];
    const int* pos = (const int*)d_in[1];  // row0 = src, row1 = dst
    const int* neg = (const int*)d_in[2];
    const float* W1 = (const float*)d_in[3];
    const float* b1 = (const float*)d_in[4];
    const float* W2 = (const float*)d_in[5];
    const float* b2 = (const float*)d_in[6];
    float* out = (float*)d_out;

    // workspace layout
    float* A = (float*)d_ws;                        // h1 [N,128]; later h2 [N,64]
    float* B = A + (size_t)N_NODES * 128;           // z1 [N,128]; later z2 [N,64]
    float* dinv = B + (size_t)N_NODES * 128;        // [N]
    int* hist = (int*)(dinv + N_NODES);             // [N]
    int* rowstart = hist + N_NODES;                 // [N+1]
    int* cursor = rowstart + N_NODES + 1;           // [N]
    int* adj = cursor + N_NODES;                    // [N_POS]
    int* partials = adj + N_POS;                    // [128]

    const int* pos_src = pos;
    const int* pos_dst = pos + N_POS;

    constexpr int NB_SCAN = (N_NODES + 1023) / 1024;  // 98

    // ---- CSR build + dinv ----
    hipMemsetAsync(hist, 0, N_NODES * sizeof(int), stream);
    hist_count<<<(N_POS + 255) / 256, 256, 0, stream>>>(pos_dst, hist, N_POS);
    scan_reduce<<<NB_SCAN, 256, 0, stream>>>(hist, partials, N_NODES);
    scan_partials<<<1, 128, 0, stream>>>(partials, NB_SCAN);
    scan_final<<<NB_SCAN, 256, 0, stream>>>(hist, partials, rowstart, cursor, dinv, N_NODES);
    csr_fill<<<(N_POS + 255) / 256, 256, 0, stream>>>(pos_src, pos_dst, cursor, adj, N_POS);

    // ---- layer 1 ----
    linear2<HIDDEN, 512><<<(N_NODES + 63) / 64, 512, 0, stream>>>(x, W1, A, N_NODES);
    agg_pull<HIDDEN, true><<<(N_NODES + 3) / 4, 256, 0, stream>>>(rowstart, adj, dinv, A, b1, B,
                                                                  N_NODES);

    // ---- layer 2 ----
    float* h2 = A;  // [N,64]
    linear2<OUT_CH, 256><<<(N_NODES + 63) / 64, 256, 0, stream>>>(B, W2, h2, N_NODES);
    float* z2 = B;  // [N,64]
    agg_pull<OUT_CH, false><<<(N_NODES + 3) / 4, 256, 0, stream>>>(rowstart, adj, dinv, h2, b2, z2,
                                                                   N_NODES);

    // ---- decode ----
    decode_kernel<<<(N_POS + N_NEG + 3) / 4, 256, 0, stream>>>(pos, neg, z2, out);
}